// Round 6
// baseline (1373.937 us; speedup 1.0000x reference)
//
#include <hip/hip_runtime.h>
#include <hip/hip_bf16.h>
#include <stdint.h>

typedef short bf16x8 __attribute__((ext_vector_type(8)));
typedef float f32x4 __attribute__((ext_vector_type(4)));
typedef unsigned int u32x2 __attribute__((ext_vector_type(2)));
typedef unsigned int u32x4 __attribute__((ext_vector_type(4)));

__device__ __forceinline__ unsigned short f2bf(float f) {
  union { float f; unsigned u; } x; x.f = f;
  unsigned r = x.u + 0x7FFFu + ((x.u >> 16) & 1u);
  return (unsigned short)(r >> 16);
}

// packed 2xf32 -> 2xbf16 (v_cvt_pk_bf16_f32 on gfx950)
__device__ __forceinline__ unsigned pk2bf(float a, float b) {
  union { __hip_bfloat162 h; unsigned u; } x;
  x.h = __float22bfloat162_rn(make_float2(a, b));
  return x.u;
}

// 2^x via v_exp_f32
__device__ __forceinline__ float exp2_fast(float x) {
#if __has_builtin(__builtin_amdgcn_exp2f)
  return __builtin_amdgcn_exp2f(x);
#else
  float r; asm("v_exp_f32 %0, %1" : "=v"(r) : "v"(x)); return r;
#endif
}

typedef const __attribute__((address_space(1))) unsigned int* gptr_t;
typedef __attribute__((address_space(3))) unsigned int* lptr_t;
__device__ __forceinline__ void gll16(const void* g, void* l) {
  __builtin_amdgcn_global_load_lds((gptr_t)g, (lptr_t)l, 16, 0, 0);
}

// scale folded into Q at projection time: exp(s/8) = 2^(s * 0.125 * log2 e)
#define QSCALE 0.18033688011116f

// ---------------- W transpose: [K=1024][N=1024] fp32 -> [N][K] bf16 ----------
__global__ __launch_bounds__(1024) void wt_kernel(const float* __restrict__ Wq,
                                                  const float* __restrict__ Wk,
                                                  const float* __restrict__ Wv,
                                                  unsigned short* __restrict__ wt) {
  const float* W = blockIdx.z == 0 ? Wq : (blockIdx.z == 1 ? Wk : Wv);
  unsigned short* o = wt + (size_t)blockIdx.z * 1048576;
  __shared__ float t[32][33];
  int tx = threadIdx.x, ty = threadIdx.y;
  t[ty][tx] = W[(size_t)(blockIdx.y * 32 + ty) * 1024 + blockIdx.x * 32 + tx];
  __syncthreads();
  o[(size_t)(blockIdx.x * 32 + ty) * 1024 + blockIdx.y * 32 + tx] = f2bf(t[tx][ty]);
}

// ---------------- X fp32 -> bf16 (Q,K,V concatenated) ------------------------
__global__ __launch_bounds__(256) void cvt_kernel(const float* __restrict__ Q,
                                                  const float* __restrict__ K,
                                                  const float* __restrict__ V,
                                                  unsigned short* __restrict__ out) {
  int y = blockIdx.y;
  const float* s = y == 0 ? Q : (y == 1 ? K : V);
  unsigned short* o = out + (size_t)y * 8388608;
  size_t idx = ((size_t)blockIdx.x * 256 + threadIdx.x) * 8;
  float4 f0 = *(const float4*)(s + idx);
  float4 f1 = *(const float4*)(s + idx + 4);
  u32x4 r = {pk2bf(f0.x, f0.y), pk2bf(f0.z, f0.w), pk2bf(f1.x, f1.y), pk2bf(f1.z, f1.w)};
  *(u32x4*)(o + idx) = r;
}

// ---------------- projection GEMM: C[8192,1024] = Xb @ W^T + b ---------------
// BM=BN=256, BK=64, 512 thr (8 waves as 2M x 4N, wave tile 128x64, acc[8][4]).
// WHY 256x256: rounds 3-5 proved proj is NOT schedule-bound -- every sync
// variant (counted vmcnt, 3-buf, 1-3 blk/CU, 128^2 / 256x128) landed at
// 119-127us. Invariant: 603MB staged through LDS from L2/L3 at ~5TB/s
// effective = the wall. BN=256 cuts A re-staging 8x->4x: staged bytes
// 603MB -> 384MB (A 192 + B 192). Sync structure identical to r5
// (stage-ahead + syncthreads); K-accumulation order unchanged.
// LDS 2 x 64KB = 128KB, 1 block/CU, grid (32,4,3)=384 blocks.
// Folds: p==0 (Q) scaled by QSCALE; p==2 (V) rows scaled by mask[b,s].
__global__ __launch_bounds__(512, 2) void proj_kernel(
    const unsigned short* __restrict__ Xb, const unsigned short* __restrict__ wt,
    const float* __restrict__ bq, const float* __restrict__ bk, const float* __restrict__ bv,
    const float* __restrict__ mask,
    unsigned short* __restrict__ qo, unsigned short* __restrict__ ko, unsigned short* __restrict__ vo) {
  int p = blockIdx.z;
  const unsigned short* X = Xb + (size_t)p * 8388608;
  const unsigned short* Wt = wt + (size_t)p * 1048576;
  const float* bias = p == 0 ? bq : (p == 1 ? bk : bv);
  unsigned short* out = p == 0 ? qo : (p == 1 ? ko : vo);

  // per buffer (32768 shorts = 64KB):
  //   [0..16383]     = B (Wt): 32 subtiles (16 n-sub x 2 kt) x 512 shorts
  //   [16384..32767] = A (X) : 32 subtiles (16 m-sub x 2 kt) x 512 shorts
  __shared__ __align__(16) unsigned short sbuf[2][32768];  // 2 x 64KB

  int tid = threadIdx.x;
  int lane = tid & 63, w = tid >> 6;
  int l15 = lane & 15, quad = lane >> 4;
  int wm = w >> 2, wn = w & 3;          // 2M x 4N wave grid, wave tile 128x64
  int m0 = blockIdx.x * 256, n0 = blockIdx.y * 256;

  // per-wave staging: 4 A + 4 B subtiles (stj = w*4+j, 32 each total).
  // Subtile = 16 rows x 32 k bf16 = 1KB; lane l15 = row, quad*8 = k-chunk.
  const unsigned short* asrc[4];
  const unsigned short* bsrc[4];
#pragma unroll
  for (int j = 0; j < 4; ++j) {
    int stj = w * 4 + j, kt = stj >> 4, t = stj & 15;
    asrc[j] = X  + (size_t)(m0 + t * 16 + l15) * 1024 + kt * 32 + quad * 8;
    bsrc[j] = Wt + (size_t)(n0 + t * 16 + l15) * 1024 + kt * 32 + quad * 8;
  }

#define PSTAGE(bi, k0)                                                 \
  do {                                                                 \
    _Pragma("unroll")                                                  \
    for (int j = 0; j < 4; ++j) {                                      \
      gll16(asrc[j] + (k0), &sbuf[bi][16384 + (w * 4 + j) * 512]);     \
      gll16(bsrc[j] + (k0), &sbuf[bi][(w * 4 + j) * 512]);             \
    }                                                                  \
  } while (0)

  f32x4 acc[8][4] = {};

  PSTAGE(0, 0);
  __syncthreads();

  for (int kk = 0; kk < 16; ++kk) {
    int cur = kk & 1;
    if (kk < 15) PSTAGE(cur ^ 1, (kk + 1) * 64);

#pragma unroll
    for (int kt = 0; kt < 2; ++kt) {
      bf16x8 bfr[4];
#pragma unroll
      for (int j = 0; j < 4; ++j)
        bfr[j] = *(const bf16x8*)&sbuf[cur][(kt * 16 + wn * 4 + j) * 512 + lane * 8];
#pragma unroll
      for (int i = 0; i < 8; ++i) {
        bf16x8 af = *(const bf16x8*)&sbuf[cur][16384 + (kt * 16 + wm * 8 + i) * 512 + lane * 8];
#pragma unroll
        for (int j = 0; j < 4; ++j)
          acc[i][j] = __builtin_amdgcn_mfma_f32_16x16x32_bf16(af, bfr[j], acc[i][j], 0, 0, 0);
      }
    }
    __syncthreads();
  }
#undef PSTAGE

  // epilogue: +bias, fold scale/mask, cast bf16, scatter q/k [B,H,S,64] or v^T [B,H,64,S]
  bool isv = (p == 2);
  bool isq = (p == 0);
  for (int j = 0; j < 4; ++j) {
    int n = n0 + wn * 64 + j * 16 + l15;
    float bl = bias[n];
    int h = n >> 6, d = n & 63;
    for (int i = 0; i < 8; ++i) {
      for (int r = 0; r < 4; ++r) {
        int m = m0 + wm * 128 + i * 16 + quad * 4 + r;
        int b = m >> 11, s = m & 2047;
        float val = acc[i][j][r] + bl;
        if (isq) val *= QSCALE;
        if (isv) val *= mask[m];
        size_t idx;
        if (isv) idx = ((size_t)((b * 16 + h) * 64 + d) << 11) + s;
        else     idx = ((size_t)((b * 16 + h) * 2048 + s) << 6) + d;
        out[idx] = f2bf(val);
      }
    }
  }
}

// ---------------- fused attention ------------------------------------------
// grid (8,16,4), 512 thr = 8 waves, wave owns 32 q-rows (QBLK=256).
// KVBLK=64, double-buffered K/V staging; prefetch t+1 issued before compute of
// tile t. Per-wave P region (no cross-wave barrier for P). One barrier/tile.
// exp scale pre-folded into Q (2^s); mask pre-folded into V rows and applied
// to the denominator via a mask B-fragment in place of the all-ones fragment.
__global__ __launch_bounds__(512, 4) void attn_kernel(
    const unsigned short* __restrict__ q, const unsigned short* __restrict__ k,
    const unsigned short* __restrict__ vT, const float* __restrict__ mask,
    float* __restrict__ out) {
  int qb = blockIdx.x, h = blockIdx.y, b = blockIdx.z;
  int tid = threadIdx.x, lane = tid & 63, w = tid >> 6;
  int l15 = lane & 15, quad = lane >> 4;

  __shared__ __align__(16) unsigned short kbuf[2][4096];  // 2 x 8KB  K tile [64 keys][64 d] frag-layout
  __shared__ __align__(16) unsigned short vbuf[2][4096];  // 2 x 8KB  V^T tile [64 dv][64 keys] frag-layout
  __shared__ __align__(16) unsigned short pbuf[8][2048];  // 8 waves x 4KB P (64 keys x 32 qrows bf16)

  const unsigned short* qp = q + (size_t)(b * 16 + h) * 2048 * 64;
  const unsigned short* kp = k + (size_t)(b * 16 + h) * 2048 * 64;
  const unsigned short* vp = vT + (size_t)(b * 16 + h) * 64 * 2048;
  const float* mp = mask + (size_t)b * 2048;

  // Q fragments (B-operand of S^T): lane holds qrow = nt*16+l15, d = kt*32+quad*8+j
  bf16x8 aq[2][2];
  for (int nt = 0; nt < 2; ++nt)
    for (int kt = 0; kt < 2; ++kt)
      aq[nt][kt] = *(const bf16x8*)(qp + (size_t)(qb * 256 + w * 32 + nt * 16 + l15) * 64 + kt * 32 + quad * 8);

  f32x4 oacc[2][4] = {};
  f32x4 dacc[2] = {};

  unsigned short* pw = pbuf[w];

  // stage slot w (one K slot + one V slot per wave, 16B/lane):
  int skt = w >> 2, sm = w & 3;
  const unsigned short* ksrc0 = kp + (size_t)(sm * 16 + l15) * 64 + skt * 32 + quad * 8;
  const unsigned short* vsrc0 = vp + (size_t)(sm * 16 + l15) * 2048 + skt * 32 + quad * 8;

#define STAGE(bi, t)                                    \
  do {                                                  \
    gll16(ksrc0 + (size_t)(t) * 64 * 64, &kbuf[bi][w * 512]); \
    gll16(vsrc0 + (size_t)(t) * 64,      &vbuf[bi][w * 512]); \
  } while (0)

  STAGE(0, 0);
  __syncthreads();

  for (int t = 0; t < 32; ++t) {
    int cur = t & 1;
    if (t + 1 < 32) STAGE(cur ^ 1, t + 1);

    // S^T = K Q^T : D col = qrow (nt*16+l15), row = key (m*16 + quad*4 + r)
    f32x4 sacc[4][2] = {};
    __builtin_amdgcn_s_setprio(1);
    for (int m = 0; m < 4; ++m)
      for (int kt = 0; kt < 2; ++kt) {
        bf16x8 ak = *(const bf16x8*)&kbuf[cur][(kt * 4 + m) * 512 + lane * 8];
        sacc[m][0] = __builtin_amdgcn_mfma_f32_16x16x32_bf16(ak, aq[0][kt], sacc[m][0], 0, 0, 0);
        sacc[m][1] = __builtin_amdgcn_mfma_f32_16x16x32_bf16(ak, aq[1][kt], sacc[m][1], 0, 0, 0);
      }
    __builtin_amdgcn_s_setprio(0);

    // P^T values: 2^S (scale pre-folded into Q), packed bf16 pairs -> LDS b64
    for (int m = 0; m < 4; ++m)
      for (int nt = 0; nt < 2; ++nt) {
        float e0 = exp2_fast(sacc[m][nt][0]);
        float e1 = exp2_fast(sacc[m][nt][1]);
        float e2 = exp2_fast(sacc[m][nt][2]);
        float e3 = exp2_fast(sacc[m][nt][3]);
        u32x2 wv = {pk2bf(e0, e1), pk2bf(e2, e3)};
        *(u32x2*)&pw[(nt * 4 + m) * 256 + lane * 4] = wv;
      }

    // O += P V', den += P @ mask. A-frag: m=qrow (mt*16+l15), keys kt*32+quad*8+j
    int kbase = t * 64;
    for (int kt = 0; kt < 2; ++kt) {
      int m = kt * 2 + (quad >> 1);
      int srcl = ((quad & 1) * 2) * 16 + l15;
      bf16x8 pa[2];
      for (int mt = 0; mt < 2; ++mt) {
        union { u32x2 p[2]; bf16x8 v; } u;
        int base = (mt * 4 + m) * 256 + srcl * 4;
        u.p[0] = *(const u32x2*)&pw[base];
        u.p[1] = *(const u32x2*)&pw[base + 64];
        pa[mt] = u.v;
      }
      // mask B-fragment: B[k][*] = mask[key], key = kbase + kt*32 + quad*8 + j
      float4 m0v = *(const float4*)&mp[kbase + kt * 32 + quad * 8];
      float4 m1v = *(const float4*)&mp[kbase + kt * 32 + quad * 8 + 4];
      union { u32x4 u; bf16x8 v; } mu;
      mu.u = (u32x4){pk2bf(m0v.x, m0v.y), pk2bf(m0v.z, m0v.w),
                     pk2bf(m1v.x, m1v.y), pk2bf(m1v.z, m1v.w)};
      __builtin_amdgcn_s_setprio(1);
      dacc[0] = __builtin_amdgcn_mfma_f32_16x16x32_bf16(pa[0], mu.v, dacc[0], 0, 0, 0);
      dacc[1] = __builtin_amdgcn_mfma_f32_16x16x32_bf16(pa[1], mu.v, dacc[1], 0, 0, 0);
      for (int nt = 0; nt < 4; ++nt) {
        bf16x8 bv = *(const bf16x8*)&vbuf[cur][(kt * 4 + nt) * 512 + lane * 8];
        oacc[0][nt] = __builtin_amdgcn_mfma_f32_16x16x32_bf16(pa[0], bv, oacc[0][nt], 0, 0, 0);
        oacc[1][nt] = __builtin_amdgcn_mfma_f32_16x16x32_bf16(pa[1], bv, oacc[1][nt], 0, 0, 0);
      }
      __builtin_amdgcn_s_setprio(0);
    }
    __syncthreads();
  }
#undef STAGE

  // epilogue: out[b][s][h*64+dv] = O / (den + 1e-8), fp32
  for (int mt = 0; mt < 2; ++mt)
    for (int r = 0; r < 4; ++r) {
      int s = qb * 256 + w * 32 + mt * 16 + quad * 4 + r;
      float rden = 1.0f / (dacc[mt][r] + 1e-8f);
      for (int nt = 0; nt < 4; ++nt) {
        int dv = nt * 16 + l15;
        out[(size_t)(b * 2048 + s) * 1024 + h * 64 + dv] = oacc[mt][nt][r] * rden;
      }
    }
}

extern "C" void kernel_launch(void* const* d_in, const int* in_sizes, int n_in,
                              void* d_out, int out_size, void* d_ws, size_t ws_size,
                              hipStream_t stream) {
  const float* Q    = (const float*)d_in[0];
  const float* K    = (const float*)d_in[1];
  const float* V    = (const float*)d_in[2];
  const float* mask = (const float*)d_in[3];
  const float* Wq   = (const float*)d_in[4];
  const float* bq   = (const float*)d_in[5];
  const float* Wk   = (const float*)d_in[6];
  const float* bk   = (const float*)d_in[7];
  const float* Wv   = (const float*)d_in[8];
  const float* bv   = (const float*)d_in[9];

  char* ws = (char*)d_ws;
  unsigned short* wt = (unsigned short*)ws;                  // 6MB: 3 x bf16 W^T
  unsigned short* qb = (unsigned short*)(ws + 6291456);      // 16MB [B,H,S,64] (pre-scaled)
  unsigned short* kb = (unsigned short*)(ws + 23068672);     // 16MB [B,H,S,64]
  unsigned short* vb = (unsigned short*)(ws + 39845888);     // 16MB [B,H,64,S] (mask-folded)
  unsigned short* xb = (unsigned short*)(ws + 56623104);     // 48MB bf16 Q,K,V

  hipLaunchKernelGGL(wt_kernel, dim3(32, 32, 3), dim3(32, 32), 0, stream, Wq, Wk, Wv, wt);
  hipLaunchKernelGGL(cvt_kernel, dim3(4096, 3), dim3(256), 0, stream, Q, K, V, xb);
  hipLaunchKernelGGL(proj_kernel, dim3(32, 4, 3), dim3(512), 0, stream,
                     xb, wt, bq, bk, bv, mask, qb, kb, vb);
  hipLaunchKernelGGL(attn_kernel, dim3(8, 16, 4), dim3(512), 0, stream,
                     qb, kb, vb, mask, (float*)d_out);
}

// Round 7
// 381.705 us; speedup vs baseline: 3.5995x; 3.5995x over previous
//
#include <hip/hip_runtime.h>
#include <hip/hip_bf16.h>
#include <stdint.h>

typedef short bf16x8 __attribute__((ext_vector_type(8)));
typedef float f32x4 __attribute__((ext_vector_type(4)));
typedef unsigned int u32x2 __attribute__((ext_vector_type(2)));
typedef unsigned int u32x4 __attribute__((ext_vector_type(4)));

__device__ __forceinline__ unsigned short f2bf(float f) {
  union { float f; unsigned u; } x; x.f = f;
  unsigned r = x.u + 0x7FFFu + ((x.u >> 16) & 1u);
  return (unsigned short)(r >> 16);
}

// packed 2xf32 -> 2xbf16 (v_cvt_pk_bf16_f32 on gfx950)
__device__ __forceinline__ unsigned pk2bf(float a, float b) {
  union { __hip_bfloat162 h; unsigned u; } x;
  x.h = __float22bfloat162_rn(make_float2(a, b));
  return x.u;
}

// 2^x via v_exp_f32
__device__ __forceinline__ float exp2_fast(float x) {
#if __has_builtin(__builtin_amdgcn_exp2f)
  return __builtin_amdgcn_exp2f(x);
#else
  float r; asm("v_exp_f32 %0, %1" : "=v"(r) : "v"(x)); return r;
#endif
}

typedef const __attribute__((address_space(1))) unsigned int* gptr_t;
typedef __attribute__((address_space(3))) unsigned int* lptr_t;
__device__ __forceinline__ void gll16(const void* g, void* l) {
  __builtin_amdgcn_global_load_lds((gptr_t)g, (lptr_t)l, 16, 0, 0);
}

// scale folded into Q at projection time: exp(s/8) = 2^(s * 0.125 * log2 e)
#define QSCALE 0.18033688011116f

// ---------------- W transpose: [K=1024][N=1024] fp32 -> [N][K] bf16 ----------
__global__ __launch_bounds__(1024) void wt_kernel(const float* __restrict__ Wq,
                                                  const float* __restrict__ Wk,
                                                  const float* __restrict__ Wv,
                                                  unsigned short* __restrict__ wt) {
  const float* W = blockIdx.z == 0 ? Wq : (blockIdx.z == 1 ? Wk : Wv);
  unsigned short* o = wt + (size_t)blockIdx.z * 1048576;
  __shared__ float t[32][33];
  int tx = threadIdx.x, ty = threadIdx.y;
  t[ty][tx] = W[(size_t)(blockIdx.y * 32 + ty) * 1024 + blockIdx.x * 32 + tx];
  __syncthreads();
  o[(size_t)(blockIdx.x * 32 + ty) * 1024 + blockIdx.y * 32 + tx] = f2bf(t[tx][ty]);
}

// ---------------- X fp32 -> bf16 (Q,K,V concatenated) ------------------------
__global__ __launch_bounds__(256) void cvt_kernel(const float* __restrict__ Q,
                                                  const float* __restrict__ K,
                                                  const float* __restrict__ V,
                                                  unsigned short* __restrict__ out) {
  int y = blockIdx.y;
  const float* s = y == 0 ? Q : (y == 1 ? K : V);
  unsigned short* o = out + (size_t)y * 8388608;
  size_t idx = ((size_t)blockIdx.x * 256 + threadIdx.x) * 8;
  float4 f0 = *(const float4*)(s + idx);
  float4 f1 = *(const float4*)(s + idx + 4);
  u32x4 r = {pk2bf(f0.x, f0.y), pk2bf(f0.z, f0.w), pk2bf(f1.x, f1.y), pk2bf(f1.z, f1.w)};
  *(u32x4*)(o + idx) = r;
}

// ---------------- projection GEMM: C[8192,1024] = Xb @ W^T + b ---------------
// BM=BN=256, BK=64, 1024 thr = 16 waves (4M x 4N), wave tile 64x64, acc[4][4].
// WHY: r6's 8-wave/acc[8][4] variant SPILLED (VGPR 108 < needed, 3GB scratch
// writes). This keeps the r5-proven per-wave register shape (88 VGPR) and gets
// the 256^2 tile via 16 waves instead. Per step: 4 gll16/wave, 32 MFMA/wave
// (128 MFMA/SIMD ~ 640cy covering the stage-ahead loads), 4 waves/SIMD TLP.
// Staged bytes 768MB (128^2) -> 384MB. launch_bounds(1024,4) caps VGPR at 128
// (16-wave block cannot launch above 128 VGPR).
// LDS 2 x 64KB = 128KB, 1 block/CU, grid (32,4,3) = 384 blocks.
// K-chunk accumulation order identical to previous versions (absmax stable).
// Folds: p==0 (Q) scaled by QSCALE; p==2 (V) rows scaled by mask[b,s].
__global__ __launch_bounds__(1024, 4) void proj_kernel(
    const unsigned short* __restrict__ Xb, const unsigned short* __restrict__ wt,
    const float* __restrict__ bq, const float* __restrict__ bk, const float* __restrict__ bv,
    const float* __restrict__ mask,
    unsigned short* __restrict__ qo, unsigned short* __restrict__ ko, unsigned short* __restrict__ vo) {
  int p = blockIdx.z;
  const unsigned short* X = Xb + (size_t)p * 8388608;
  const unsigned short* Wt = wt + (size_t)p * 1048576;
  const float* bias = p == 0 ? bq : (p == 1 ? bk : bv);
  unsigned short* out = p == 0 ? qo : (p == 1 ? ko : vo);

  // per buffer (32768 shorts = 64KB):
  //   [0..16383]     = B (Wt): 32 subtiles (kt*16 + n-sub) x 512 shorts
  //   [16384..32767] = A (X) : 32 subtiles (kt*16 + m-sub) x 512 shorts
  __shared__ __align__(16) unsigned short sbuf[2][32768];  // 2 x 64KB

  int tid = threadIdx.x;
  int lane = tid & 63, w = tid >> 6;     // w in [0,16)
  int l15 = lane & 15, quad = lane >> 4;
  int wm = w >> 2, wn = w & 3;           // 4M x 4N wave grid, wave tile 64x64
  int m0 = blockIdx.x * 256, n0 = blockIdx.y * 256;

  // per-wave staging: 2 A + 2 B subtiles (stj = w*2+j, 32 each total).
  // Subtile = 16 rows x 32 k bf16 = 1KB; lane l15 = row, quad*8 = k-chunk.
  const unsigned short* asrc[2];
  const unsigned short* bsrc[2];
#pragma unroll
  for (int j = 0; j < 2; ++j) {
    int stj = w * 2 + j, kt = stj >> 4, t = stj & 15;
    asrc[j] = X  + (size_t)(m0 + t * 16 + l15) * 1024 + kt * 32 + quad * 8;
    bsrc[j] = Wt + (size_t)(n0 + t * 16 + l15) * 1024 + kt * 32 + quad * 8;
  }

#define PSTAGE(bi, k0)                                                 \
  do {                                                                 \
    _Pragma("unroll")                                                  \
    for (int j = 0; j < 2; ++j) {                                      \
      gll16(asrc[j] + (k0), &sbuf[bi][16384 + (w * 2 + j) * 512]);     \
      gll16(bsrc[j] + (k0), &sbuf[bi][(w * 2 + j) * 512]);             \
    }                                                                  \
  } while (0)

  f32x4 acc[4][4] = {};

  PSTAGE(0, 0);
  __syncthreads();

  for (int kk = 0; kk < 16; ++kk) {
    int cur = kk & 1;
    if (kk < 15) PSTAGE(cur ^ 1, (kk + 1) * 64);

#pragma unroll
    for (int kt = 0; kt < 2; ++kt) {
      bf16x8 af[4], bfr[4];
#pragma unroll
      for (int i = 0; i < 4; ++i)
        af[i] = *(const bf16x8*)&sbuf[cur][16384 + (kt * 16 + wm * 4 + i) * 512 + lane * 8];
#pragma unroll
      for (int j = 0; j < 4; ++j)
        bfr[j] = *(const bf16x8*)&sbuf[cur][(kt * 16 + wn * 4 + j) * 512 + lane * 8];
#pragma unroll
      for (int i = 0; i < 4; ++i)
#pragma unroll
        for (int j = 0; j < 4; ++j)
          acc[i][j] = __builtin_amdgcn_mfma_f32_16x16x32_bf16(af[i], bfr[j], acc[i][j], 0, 0, 0);
    }
    __syncthreads();
  }
#undef PSTAGE

  // epilogue: +bias, fold scale/mask, cast bf16, scatter q/k [B,H,S,64] or v^T [B,H,64,S]
  bool isv = (p == 2);
  bool isq = (p == 0);
  for (int j = 0; j < 4; ++j) {
    int n = n0 + wn * 64 + j * 16 + l15;
    float bl = bias[n];
    int h = n >> 6, d = n & 63;
    for (int i = 0; i < 4; ++i) {
      for (int r = 0; r < 4; ++r) {
        int m = m0 + wm * 64 + i * 16 + quad * 4 + r;
        int b = m >> 11, s = m & 2047;
        float val = acc[i][j][r] + bl;
        if (isq) val *= QSCALE;
        if (isv) val *= mask[m];
        size_t idx;
        if (isv) idx = ((size_t)((b * 16 + h) * 64 + d) << 11) + s;
        else     idx = ((size_t)((b * 16 + h) * 2048 + s) << 6) + d;
        out[idx] = f2bf(val);
      }
    }
  }
}

// ---------------- fused attention ------------------------------------------
// grid (8,16,4), 512 thr = 8 waves, wave owns 32 q-rows (QBLK=256).
// KVBLK=64, double-buffered K/V staging; prefetch t+1 issued before compute of
// tile t. Per-wave P region (no cross-wave barrier for P). One barrier/tile.
// exp scale pre-folded into Q (2^s); mask pre-folded into V rows and applied
// to the denominator via a mask B-fragment in place of the all-ones fragment.
__global__ __launch_bounds__(512, 4) void attn_kernel(
    const unsigned short* __restrict__ q, const unsigned short* __restrict__ k,
    const unsigned short* __restrict__ vT, const float* __restrict__ mask,
    float* __restrict__ out) {
  int qb = blockIdx.x, h = blockIdx.y, b = blockIdx.z;
  int tid = threadIdx.x, lane = tid & 63, w = tid >> 6;
  int l15 = lane & 15, quad = lane >> 4;

  __shared__ __align__(16) unsigned short kbuf[2][4096];  // 2 x 8KB  K tile [64 keys][64 d] frag-layout
  __shared__ __align__(16) unsigned short vbuf[2][4096];  // 2 x 8KB  V^T tile [64 dv][64 keys] frag-layout
  __shared__ __align__(16) unsigned short pbuf[8][2048];  // 8 waves x 4KB P (64 keys x 32 qrows bf16)

  const unsigned short* qp = q + (size_t)(b * 16 + h) * 2048 * 64;
  const unsigned short* kp = k + (size_t)(b * 16 + h) * 2048 * 64;
  const unsigned short* vp = vT + (size_t)(b * 16 + h) * 64 * 2048;
  const float* mp = mask + (size_t)b * 2048;

  // Q fragments (B-operand of S^T): lane holds qrow = nt*16+l15, d = kt*32+quad*8+j
  bf16x8 aq[2][2];
  for (int nt = 0; nt < 2; ++nt)
    for (int kt = 0; kt < 2; ++kt)
      aq[nt][kt] = *(const bf16x8*)(qp + (size_t)(qb * 256 + w * 32 + nt * 16 + l15) * 64 + kt * 32 + quad * 8);

  f32x4 oacc[2][4] = {};
  f32x4 dacc[2] = {};

  unsigned short* pw = pbuf[w];

  // stage slot w (one K slot + one V slot per wave, 16B/lane):
  int skt = w >> 2, sm = w & 3;
  const unsigned short* ksrc0 = kp + (size_t)(sm * 16 + l15) * 64 + skt * 32 + quad * 8;
  const unsigned short* vsrc0 = vp + (size_t)(sm * 16 + l15) * 2048 + skt * 32 + quad * 8;

#define STAGE(bi, t)                                    \
  do {                                                  \
    gll16(ksrc0 + (size_t)(t) * 64 * 64, &kbuf[bi][w * 512]); \
    gll16(vsrc0 + (size_t)(t) * 64,      &vbuf[bi][w * 512]); \
  } while (0)

  STAGE(0, 0);
  __syncthreads();

  for (int t = 0; t < 32; ++t) {
    int cur = t & 1;
    if (t + 1 < 32) STAGE(cur ^ 1, t + 1);

    // S^T = K Q^T : D col = qrow (nt*16+l15), row = key (m*16 + quad*4 + r)
    f32x4 sacc[4][2] = {};
    __builtin_amdgcn_s_setprio(1);
    for (int m = 0; m < 4; ++m)
      for (int kt = 0; kt < 2; ++kt) {
        bf16x8 ak = *(const bf16x8*)&kbuf[cur][(kt * 4 + m) * 512 + lane * 8];
        sacc[m][0] = __builtin_amdgcn_mfma_f32_16x16x32_bf16(ak, aq[0][kt], sacc[m][0], 0, 0, 0);
        sacc[m][1] = __builtin_amdgcn_mfma_f32_16x16x32_bf16(ak, aq[1][kt], sacc[m][1], 0, 0, 0);
      }
    __builtin_amdgcn_s_setprio(0);

    // P^T values: 2^S (scale pre-folded into Q), packed bf16 pairs -> LDS b64
    for (int m = 0; m < 4; ++m)
      for (int nt = 0; nt < 2; ++nt) {
        float e0 = exp2_fast(sacc[m][nt][0]);
        float e1 = exp2_fast(sacc[m][nt][1]);
        float e2 = exp2_fast(sacc[m][nt][2]);
        float e3 = exp2_fast(sacc[m][nt][3]);
        u32x2 wv = {pk2bf(e0, e1), pk2bf(e2, e3)};
        *(u32x2*)&pw[(nt * 4 + m) * 256 + lane * 4] = wv;
      }

    // O += P V', den += P @ mask. A-frag: m=qrow (mt*16+l15), keys kt*32+quad*8+j
    int kbase = t * 64;
    for (int kt = 0; kt < 2; ++kt) {
      int m = kt * 2 + (quad >> 1);
      int srcl = ((quad & 1) * 2) * 16 + l15;
      bf16x8 pa[2];
      for (int mt = 0; mt < 2; ++mt) {
        union { u32x2 p[2]; bf16x8 v; } u;
        int base = (mt * 4 + m) * 256 + srcl * 4;
        u.p[0] = *(const u32x2*)&pw[base];
        u.p[1] = *(const u32x2*)&pw[base + 64];
        pa[mt] = u.v;
      }
      // mask B-fragment: B[k][*] = mask[key], key = kbase + kt*32 + quad*8 + j
      float4 m0v = *(const float4*)&mp[kbase + kt * 32 + quad * 8];
      float4 m1v = *(const float4*)&mp[kbase + kt * 32 + quad * 8 + 4];
      union { u32x4 u; bf16x8 v; } mu;
      mu.u = (u32x4){pk2bf(m0v.x, m0v.y), pk2bf(m0v.z, m0v.w),
                     pk2bf(m1v.x, m1v.y), pk2bf(m1v.z, m1v.w)};
      __builtin_amdgcn_s_setprio(1);
      dacc[0] = __builtin_amdgcn_mfma_f32_16x16x32_bf16(pa[0], mu.v, dacc[0], 0, 0, 0);
      dacc[1] = __builtin_amdgcn_mfma_f32_16x16x32_bf16(pa[1], mu.v, dacc[1], 0, 0, 0);
      for (int nt = 0; nt < 4; ++nt) {
        bf16x8 bv = *(const bf16x8*)&vbuf[cur][(kt * 4 + nt) * 512 + lane * 8];
        oacc[0][nt] = __builtin_amdgcn_mfma_f32_16x16x32_bf16(pa[0], bv, oacc[0][nt], 0, 0, 0);
        oacc[1][nt] = __builtin_amdgcn_mfma_f32_16x16x32_bf16(pa[1], bv, oacc[1][nt], 0, 0, 0);
      }
      __builtin_amdgcn_s_setprio(0);
    }
    __syncthreads();
  }
#undef STAGE

  // epilogue: out[b][s][h*64+dv] = O / (den + 1e-8), fp32
  for (int mt = 0; mt < 2; ++mt)
    for (int r = 0; r < 4; ++r) {
      int s = qb * 256 + w * 32 + mt * 16 + quad * 4 + r;
      float rden = 1.0f / (dacc[mt][r] + 1e-8f);
      for (int nt = 0; nt < 4; ++nt) {
        int dv = nt * 16 + l15;
        out[(size_t)(b * 2048 + s) * 1024 + h * 64 + dv] = oacc[mt][nt][r] * rden;
      }
    }
}

extern "C" void kernel_launch(void* const* d_in, const int* in_sizes, int n_in,
                              void* d_out, int out_size, void* d_ws, size_t ws_size,
                              hipStream_t stream) {
  const float* Q    = (const float*)d_in[0];
  const float* K    = (const float*)d_in[1];
  const float* V    = (const float*)d_in[2];
  const float* mask = (const float*)d_in[3];
  const float* Wq   = (const float*)d_in[4];
  const float* bq   = (const float*)d_in[5];
  const float* Wk   = (const float*)d_in[6];
  const float* bk   = (const float*)d_in[7];
  const float* Wv   = (const float*)d_in[8];
  const float* bv   = (const float*)d_in[9];

  char* ws = (char*)d_ws;
  unsigned short* wt = (unsigned short*)ws;                  // 6MB: 3 x bf16 W^T
  unsigned short* qb = (unsigned short*)(ws + 6291456);      // 16MB [B,H,S,64] (pre-scaled)
  unsigned short* kb = (unsigned short*)(ws + 23068672);     // 16MB [B,H,S,64]
  unsigned short* vb = (unsigned short*)(ws + 39845888);     // 16MB [B,H,64,S] (mask-folded)
  unsigned short* xb = (unsigned short*)(ws + 56623104);     // 48MB bf16 Q,K,V

  hipLaunchKernelGGL(wt_kernel, dim3(32, 32, 3), dim3(32, 32), 0, stream, Wq, Wk, Wv, wt);
  hipLaunchKernelGGL(cvt_kernel, dim3(4096, 3), dim3(256), 0, stream, Q, K, V, xb);
  hipLaunchKernelGGL(proj_kernel, dim3(32, 4, 3), dim3(1024), 0, stream,
                     xb, wt, bq, bk, bv, mask, qb, kb, vb);
  hipLaunchKernelGGL(attn_kernel, dim3(8, 16, 4), dim3(512), 0, stream,
                     qb, kb, vb, mask, (float*)d_out);
}

// Round 9
// 353.395 us; speedup vs baseline: 3.8878x; 1.0801x over previous
//
#include <hip/hip_runtime.h>
#include <hip/hip_bf16.h>
#include <stdint.h>

typedef short bf16x8 __attribute__((ext_vector_type(8)));
typedef float f32x4 __attribute__((ext_vector_type(4)));
typedef unsigned int u32x2 __attribute__((ext_vector_type(2)));
typedef unsigned int u32x4 __attribute__((ext_vector_type(4)));

__device__ __forceinline__ unsigned short f2bf(float f) {
  union { float f; unsigned u; } x; x.f = f;
  unsigned r = x.u + 0x7FFFu + ((x.u >> 16) & 1u);
  return (unsigned short)(r >> 16);
}

// packed 2xf32 -> 2xbf16 (v_cvt_pk_bf16_f32 on gfx950)
__device__ __forceinline__ unsigned pk2bf(float a, float b) {
  union { __hip_bfloat162 h; unsigned u; } x;
  x.h = __float22bfloat162_rn(make_float2(a, b));
  return x.u;
}

// 2^x via v_exp_f32
__device__ __forceinline__ float exp2_fast(float x) {
#if __has_builtin(__builtin_amdgcn_exp2f)
  return __builtin_amdgcn_exp2f(x);
#else
  float r; asm("v_exp_f32 %0, %1" : "=v"(r) : "v"(x)); return r;
#endif
}

typedef const __attribute__((address_space(1))) unsigned int* gptr_t;
typedef __attribute__((address_space(3))) unsigned int* lptr_t;
__device__ __forceinline__ void gll16(const void* g, void* l) {
  __builtin_amdgcn_global_load_lds((gptr_t)g, (lptr_t)l, 16, 0, 0);
}

// scale folded into Q at projection time: exp(s/8) = 2^(s * 0.125 * log2 e)
#define QSCALE 0.18033688011116f

// ---------------- W transpose: [K=1024][N=1024] fp32 -> [N][K] bf16 ----------
__global__ __launch_bounds__(1024) void wt_kernel(const float* __restrict__ Wq,
                                                  const float* __restrict__ Wk,
                                                  const float* __restrict__ Wv,
                                                  unsigned short* __restrict__ wt) {
  const float* W = blockIdx.z == 0 ? Wq : (blockIdx.z == 1 ? Wk : Wv);
  unsigned short* o = wt + (size_t)blockIdx.z * 1048576;
  __shared__ float t[32][33];
  int tx = threadIdx.x, ty = threadIdx.y;
  t[ty][tx] = W[(size_t)(blockIdx.y * 32 + ty) * 1024 + blockIdx.x * 32 + tx];
  __syncthreads();
  o[(size_t)(blockIdx.x * 32 + ty) * 1024 + blockIdx.y * 32 + tx] = f2bf(t[tx][ty]);
}

// ---------------- X fp32 -> bf16 (Q,K,V concatenated) ------------------------
__global__ __launch_bounds__(256) void cvt_kernel(const float* __restrict__ Q,
                                                  const float* __restrict__ K,
                                                  const float* __restrict__ V,
                                                  unsigned short* __restrict__ out) {
  int y = blockIdx.y;
  const float* s = y == 0 ? Q : (y == 1 ? K : V);
  unsigned short* o = out + (size_t)y * 8388608;
  size_t idx = ((size_t)blockIdx.x * 256 + threadIdx.x) * 8;
  float4 f0 = *(const float4*)(s + idx);
  float4 f1 = *(const float4*)(s + idx + 4);
  u32x4 r = {pk2bf(f0.x, f0.y), pk2bf(f0.z, f0.w), pk2bf(f1.x, f1.y), pk2bf(f1.z, f1.w)};
  *(u32x4*)(o + idx) = r;
}

// ---------------- projection GEMM: C[8192,1024] = Xb @ W^T + b ---------------
// K-loop: r4's best-measured structure (119.6us): 128x128 tile, BK=32,
// 3-buffer pipeline staged 2 tiles ahead, counted s_waitcnt vmcnt(4) +
// raw s_barrier. UNCHANGED.
// EPILOGUE: fold+cast into LDS (reuse sbuf, 128x136 bf16), barrier, then
// coalesced write-out (8-lane groups cover contiguous 128B segments;
// 8 dwordx4 stores/thread instead of 64 scalar shorts).
// r8 BUG FIXED: the V write-out used raw m0 in the S coordinate instead of
// (m0 & 2047) -- the batch offset is already carried by b. One-line fix.
// Folds: p==0 (Q) scaled by QSCALE; p==2 (V) rows scaled by mask[b,s].
__global__ __launch_bounds__(256, 3) void proj_kernel(
    const unsigned short* __restrict__ Xb, const unsigned short* __restrict__ wt,
    const float* __restrict__ bq, const float* __restrict__ bk, const float* __restrict__ bv,
    const float* __restrict__ mask,
    unsigned short* __restrict__ qo, unsigned short* __restrict__ ko, unsigned short* __restrict__ vo) {
  int p = blockIdx.z;
  const unsigned short* X = Xb + (size_t)p * 8388608;
  const unsigned short* Wt = wt + (size_t)p * 1048576;
  const float* bias = p == 0 ? bq : (p == 1 ? bk : bv);
  unsigned short* out = p == 0 ? qo : (p == 1 ? ko : vo);

  // per buffer: [0..4095] = B (Wt) 8 subtiles x 512, [4096..8191] = A (X)
  __shared__ __align__(16) unsigned short sbuf[3][8192];  // 48KB -> 3 blocks/CU

  int tid = threadIdx.x;
  int lane = tid & 63, w = tid >> 6;
  int l15 = lane & 15, quad = lane >> 4;
  int wm = w >> 1, wn = w & 1;
  int m0 = blockIdx.x * 128, n0 = blockIdx.y * 128;

  // per-wave staging: 4 subtiles (stj = w*4+j), each 1KB = 64 lanes x 16B.
  // stj<8: B subtile (rows n0+stj*16+l15 of Wt); else A subtile (rows of X).
  const unsigned short* src[4];
  unsigned dstoff[4];
#pragma unroll
  for (int j = 0; j < 4; ++j) {
    int stj = w * 4 + j;
    if (stj < 8) src[j] = Wt + (size_t)(n0 + stj * 16 + l15) * 1024 + quad * 8;
    else         src[j] = X  + (size_t)(m0 + (stj - 8) * 16 + l15) * 1024 + quad * 8;
    dstoff[j] = stj * 512;
  }

  f32x4 acc[4][4] = {};

#define PSTAGE(sb, t)                                           \
  do {                                                          \
    _Pragma("unroll")                                           \
    for (int j = 0; j < 4; ++j)                                 \
      gll16(src[j] + (size_t)(t) * 32, &sbuf[sb][dstoff[j]]);   \
  } while (0)

#define PCOMPUTE(cb)                                                          \
  do {                                                                        \
    bf16x8 af[4], bfr[4];                                                     \
    _Pragma("unroll")                                                         \
    for (int i = 0; i < 4; ++i)                                               \
      af[i] = *(const bf16x8*)&sbuf[cb][4096 + (wm * 4 + i) * 512 + lane * 8];\
    _Pragma("unroll")                                                         \
    for (int j = 0; j < 4; ++j)                                               \
      bfr[j] = *(const bf16x8*)&sbuf[cb][(wn * 4 + j) * 512 + lane * 8];      \
    _Pragma("unroll")                                                         \
    for (int i = 0; i < 4; ++i)                                               \
      _Pragma("unroll")                                                       \
      for (int j = 0; j < 4; ++j)                                             \
        acc[i][j] = __builtin_amdgcn_mfma_f32_16x16x32_bf16(af[i], bfr[j], acc[i][j], 0, 0, 0); \
  } while (0)

#define PSYNC(n)                                                    \
  do {                                                              \
    asm volatile("s_waitcnt vmcnt(" #n ") lgkmcnt(0)" ::: "memory");\
    __builtin_amdgcn_sched_barrier(0);                              \
    __builtin_amdgcn_s_barrier();                                   \
    __builtin_amdgcn_sched_barrier(0);                              \
  } while (0)

  // prologue: stage tiles 0,1 -> 8 loads; vmcnt(4) ensures tile 0 complete
  PSTAGE(0, 0);
  PSTAGE(1, 1);
  PSYNC(4);

  // main loop: 30 steps, unrolled x3 so buffer indices are compile-time.
  for (int g = 0; g < 10; ++g) {
    int t = g * 3;
    PSTAGE(2, t + 2);  PCOMPUTE(0);  PSYNC(4);
    PSTAGE(0, t + 3);  PCOMPUTE(1);  PSYNC(4);
    PSTAGE(1, t + 4);  PCOMPUTE(2);  PSYNC(4);
  }
  // t=30: nothing left to stage; drain tile 31's loads, then compute it.
  PCOMPUTE(0);
  PSYNC(0);
  PCOMPUTE(1);

#undef PSTAGE
#undef PCOMPUTE
#undef PSYNC

  // ---- epilogue: fold + cast into LDS, then coalesced write-out ----
  __syncthreads();  // all waves done reading sbuf; reuse as C-stage

  unsigned short* cl = &sbuf[0][0];  // 128 x 136 bf16 (34KB of the 48KB)
  bool isv = (p == 2);
  bool isq = (p == 0);

  for (int j = 0; j < 4; ++j) {
    int n = wn * 64 + j * 16 + l15;          // tile-local col
    float bl = bias[n0 + n];
    for (int i = 0; i < 4; ++i) {
      int mb = wm * 64 + i * 16 + quad * 4;  // tile-local row base
      if (isv) {
        // layout [n][m]: 4 consecutive m (r=0..3) pack into one b64 write
        union { unsigned short s4[4]; u32x2 v; } pk;
        for (int r = 0; r < 4; ++r) {
          float val = acc[i][j][r] + bl;
          val *= mask[m0 + mb + r];
          pk.s4[r] = f2bf(val);
        }
        *(u32x2*)&cl[n * 136 + mb] = pk.v;
      } else {
        // layout [m][n]
        for (int r = 0; r < 4; ++r) {
          float val = acc[i][j][r] + bl;
          if (isq) val *= QSCALE;
          cl[(mb + r) * 136 + n] = f2bf(val);
        }
      }
    }
  }
  __syncthreads();

  // write-out: 256 runs of 64 shorts (128B). run rr -> (row rr>>1, half rr&1).
  // 8 passes x (32 runs, 8 lanes each): consecutive 8 lanes cover one
  // contiguous 128B global segment -> fully coalesced dwordx4 stores.
  int b = m0 >> 11;
  int sloc = m0 & 2047;              // S coordinate base within the batch
  int ch = tid & 7;                  // 16B chunk within run
  for (int pass = 0; pass < 8; ++pass) {
    int rr = pass * 32 + (tid >> 3);
    int row = rr >> 1, half = rr & 1;
    const unsigned short* sr = &cl[row * 136 + half * 64 + ch * 8];
    unsigned short* dst;
    if (isv) {
      int nn = n0 + row;
      int h = nn >> 6, d = nn & 63;
      dst = out + (((size_t)((b * 16 + h) * 64 + d)) << 11) + sloc + half * 64 + ch * 8;
    } else {
      int s = sloc + row;
      int h = (n0 >> 6) + half;
      dst = out + (((size_t)((b * 16 + h) * 2048 + s)) << 6) + ch * 8;
    }
    *(u32x4*)dst = *(const u32x4*)sr;
  }
}

// ---------------- fused attention ------------------------------------------
// grid (8,16,4), 512 thr = 8 waves, wave owns 32 q-rows (QBLK=256).
// KVBLK=64, double-buffered K/V staging; prefetch t+1 issued before compute of
// tile t. Per-wave P region (no cross-wave barrier for P). One barrier/tile.
// exp scale pre-folded into Q (2^s); mask pre-folded into V rows and applied
// to the denominator via a mask B-fragment in place of the all-ones fragment.
__global__ __launch_bounds__(512, 4) void attn_kernel(
    const unsigned short* __restrict__ q, const unsigned short* __restrict__ k,
    const unsigned short* __restrict__ vT, const float* __restrict__ mask,
    float* __restrict__ out) {
  int qb = blockIdx.x, h = blockIdx.y, b = blockIdx.z;
  int tid = threadIdx.x, lane = tid & 63, w = tid >> 6;
  int l15 = lane & 15, quad = lane >> 4;

  __shared__ __align__(16) unsigned short kbuf[2][4096];  // 2 x 8KB  K tile [64 keys][64 d] frag-layout
  __shared__ __align__(16) unsigned short vbuf[2][4096];  // 2 x 8KB  V^T tile [64 dv][64 keys] frag-layout
  __shared__ __align__(16) unsigned short pbuf[8][2048];  // 8 waves x 4KB P (64 keys x 32 qrows bf16)

  const unsigned short* qp = q + (size_t)(b * 16 + h) * 2048 * 64;
  const unsigned short* kp = k + (size_t)(b * 16 + h) * 2048 * 64;
  const unsigned short* vp = vT + (size_t)(b * 16 + h) * 64 * 2048;
  const float* mp = mask + (size_t)b * 2048;

  // Q fragments (B-operand of S^T): lane holds qrow = nt*16+l15, d = kt*32+quad*8+j
  bf16x8 aq[2][2];
  for (int nt = 0; nt < 2; ++nt)
    for (int kt = 0; kt < 2; ++kt)
      aq[nt][kt] = *(const bf16x8*)(qp + (size_t)(qb * 256 + w * 32 + nt * 16 + l15) * 64 + kt * 32 + quad * 8);

  f32x4 oacc[2][4] = {};
  f32x4 dacc[2] = {};

  unsigned short* pw = pbuf[w];

  // stage slot w (one K slot + one V slot per wave, 16B/lane):
  int skt = w >> 2, sm = w & 3;
  const unsigned short* ksrc0 = kp + (size_t)(sm * 16 + l15) * 64 + skt * 32 + quad * 8;
  const unsigned short* vsrc0 = vp + (size_t)(sm * 16 + l15) * 2048 + skt * 32 + quad * 8;

#define STAGE(bi, t)                                    \
  do {                                                  \
    gll16(ksrc0 + (size_t)(t) * 64 * 64, &kbuf[bi][w * 512]); \
    gll16(vsrc0 + (size_t)(t) * 64,      &vbuf[bi][w * 512]); \
  } while (0)

  STAGE(0, 0);
  __syncthreads();

  for (int t = 0; t < 32; ++t) {
    int cur = t & 1;
    if (t + 1 < 32) STAGE(cur ^ 1, t + 1);

    // S^T = K Q^T : D col = qrow (nt*16+l15), row = key (m*16 + quad*4 + r)
    f32x4 sacc[4][2] = {};
    __builtin_amdgcn_s_setprio(1);
    for (int m = 0; m < 4; ++m)
      for (int kt = 0; kt < 2; ++kt) {
        bf16x8 ak = *(const bf16x8*)&kbuf[cur][(kt * 4 + m) * 512 + lane * 8];
        sacc[m][0] = __builtin_amdgcn_mfma_f32_16x16x32_bf16(ak, aq[0][kt], sacc[m][0], 0, 0, 0);
        sacc[m][1] = __builtin_amdgcn_mfma_f32_16x16x32_bf16(ak, aq[1][kt], sacc[m][1], 0, 0, 0);
      }
    __builtin_amdgcn_s_setprio(0);

    // P^T values: 2^S (scale pre-folded into Q), packed bf16 pairs -> LDS b64
    for (int m = 0; m < 4; ++m)
      for (int nt = 0; nt < 2; ++nt) {
        float e0 = exp2_fast(sacc[m][nt][0]);
        float e1 = exp2_fast(sacc[m][nt][1]);
        float e2 = exp2_fast(sacc[m][nt][2]);
        float e3 = exp2_fast(sacc[m][nt][3]);
        u32x2 wv = {pk2bf(e0, e1), pk2bf(e2, e3)};
        *(u32x2*)&pw[(nt * 4 + m) * 256 + lane * 4] = wv;
      }

    // O += P V', den += P @ mask. A-frag: m=qrow (mt*16+l15), keys kt*32+quad*8+j
    int kbase = t * 64;
    for (int kt = 0; kt < 2; ++kt) {
      int m = kt * 2 + (quad >> 1);
      int srcl = ((quad & 1) * 2) * 16 + l15;
      bf16x8 pa[2];
      for (int mt = 0; mt < 2; ++mt) {
        union { u32x2 p[2]; bf16x8 v; } u;
        int base = (mt * 4 + m) * 256 + srcl * 4;
        u.p[0] = *(const u32x2*)&pw[base];
        u.p[1] = *(const u32x2*)&pw[base + 64];
        pa[mt] = u.v;
      }
      // mask B-fragment: B[k][*] = mask[key], key = kbase + kt*32 + quad*8 + j
      float4 m0v = *(const float4*)&mp[kbase + kt * 32 + quad * 8];
      float4 m1v = *(const float4*)&mp[kbase + kt * 32 + quad * 8 + 4];
      union { u32x4 u; bf16x8 v; } mu;
      mu.u = (u32x4){pk2bf(m0v.x, m0v.y), pk2bf(m0v.z, m0v.w),
                     pk2bf(m1v.x, m1v.y), pk2bf(m1v.z, m1v.w)};
      __builtin_amdgcn_s_setprio(1);
      dacc[0] = __builtin_amdgcn_mfma_f32_16x16x32_bf16(pa[0], mu.v, dacc[0], 0, 0, 0);
      dacc[1] = __builtin_amdgcn_mfma_f32_16x16x32_bf16(pa[1], mu.v, dacc[1], 0, 0, 0);
      for (int nt = 0; nt < 4; ++nt) {
        bf16x8 bv = *(const bf16x8*)&vbuf[cur][(kt * 4 + nt) * 512 + lane * 8];
        oacc[0][nt] = __builtin_amdgcn_mfma_f32_16x16x32_bf16(pa[0], bv, oacc[0][nt], 0, 0, 0);
        oacc[1][nt] = __builtin_amdgcn_mfma_f32_16x16x32_bf16(pa[1], bv, oacc[1][nt], 0, 0, 0);
      }
      __builtin_amdgcn_s_setprio(0);
    }
    __syncthreads();
  }
#undef STAGE

  // epilogue: out[b][s][h*64+dv] = O / (den + 1e-8), fp32
  for (int mt = 0; mt < 2; ++mt)
    for (int r = 0; r < 4; ++r) {
      int s = qb * 256 + w * 32 + mt * 16 + quad * 4 + r;
      float rden = 1.0f / (dacc[mt][r] + 1e-8f);
      for (int nt = 0; nt < 4; ++nt) {
        int dv = nt * 16 + l15;
        out[(size_t)(b * 2048 + s) * 1024 + h * 64 + dv] = oacc[mt][nt][r] * rden;
      }
    }
}

extern "C" void kernel_launch(void* const* d_in, const int* in_sizes, int n_in,
                              void* d_out, int out_size, void* d_ws, size_t ws_size,
                              hipStream_t stream) {
  const float* Q    = (const float*)d_in[0];
  const float* K    = (const float*)d_in[1];
  const float* V    = (const float*)d_in[2];
  const float* mask = (const float*)d_in[3];
  const float* Wq   = (const float*)d_in[4];
  const float* bq   = (const float*)d_in[5];
  const float* Wk   = (const float*)d_in[6];
  const float* bk   = (const float*)d_in[7];
  const float* Wv   = (const float*)d_in[8];
  const float* bv   = (const float*)d_in[9];

  char* ws = (char*)d_ws;
  unsigned short* wt = (unsigned short*)ws;                  // 6MB: 3 x bf16 W^T
  unsigned short* qb = (unsigned short*)(ws + 6291456);      // 16MB [B,H,S,64] (pre-scaled)
  unsigned short* kb = (unsigned short*)(ws + 23068672);     // 16MB [B,H,S,64]
  unsigned short* vb = (unsigned short*)(ws + 39845888);     // 16MB [B,H,64,S] (mask-folded)
  unsigned short* xb = (unsigned short*)(ws + 56623104);     // 48MB bf16 Q,K,V

  hipLaunchKernelGGL(wt_kernel, dim3(32, 32, 3), dim3(32, 32), 0, stream, Wq, Wk, Wv, wt);
  hipLaunchKernelGGL(cvt_kernel, dim3(4096, 3), dim3(256), 0, stream, Q, K, V, xb);
  hipLaunchKernelGGL(proj_kernel, dim3(64, 8, 3), dim3(256), 0, stream,
                     xb, wt, bq, bk, bv, mask, qb, kb, vb);
  hipLaunchKernelGGL(attn_kernel, dim3(8, 16, 4), dim3(512), 0, stream,
                     qb, kb, vb, mask, (float*)d_out);
}